// Round 12
// baseline (239.528 us; speedup 1.0000x reference)
//
#include <hip/hip_runtime.h>
#include <hip/hip_bf16.h>

// Problem: CausalSelfAttention  B=2, T=2048, C=1024, H=16, D=64
// Round 24: BK=64 (two 32-wide panels per staging phase) on the GEMMs.
// R23 (XCD swizzle isolated) confirmed: qkv_qk 66.3->64.5, FETCH 70->41MB,
// total 238.7 best. qkv_qk remains latency-bound on the per-K-step drain
// (vmcnt(0) + 2 barriers, 32x). This round halves the drain count: stage
// TWO 32-wide panels per barrier-pair (16 iterations of 2x work). Per-panel
// layout/swizzle/frag-reads/MFMA order byte-identical -> numerics identical.
// LDS 32->64KB (qkv_qk), 12->24KB (qkv_v/proj); occupancy unchanged (grid-
// pinned at 2 blocks/CU; 2x64=128<=160KB). Dodges m132 (that was an
// occupancy loss; ours is grid-limited). attn/cvt byte-identical to R23.
// ws (62 MB): Qh 8|Ql 8|Kh 8|Kl 8|xh 8(->Yb)|xl 8(->VT)|WaTh 6|WaTl 6|WpT 2

#define B_  2
#define T_  2048
#define C_  1024
#define H_  16
#define D_  64
#define M_  (B_ * T_)      // 4096
#define N3_ (3 * C_)       // 3072

typedef __attribute__((ext_vector_type(8))) short s16x8;
typedef __attribute__((ext_vector_type(4))) short s16x4;
typedef __attribute__((ext_vector_type(4))) float f32x4;

typedef const __attribute__((address_space(1))) unsigned int gu32_t;
typedef __attribute__((address_space(3))) unsigned int lu32_t;

#define MFMA16(a, b, c) __builtin_amdgcn_mfma_f32_16x16x32_bf16(a, b, c, 0, 0, 0)

__device__ __forceinline__ void gload_lds16(const short* g, short* l) {
    __builtin_amdgcn_global_load_lds((gu32_t*)g, (lu32_t*)l, 16, 0, 0);
}

__device__ __forceinline__ float b2f(unsigned short u) {
    return __uint_as_float(((unsigned)u) << 16);
}
__device__ __forceinline__ unsigned short f2b(float f) {   // RNE bf16 round
    unsigned u = __float_as_uint(f);
    return (unsigned short)((u + 0x7FFFu + ((u >> 16) & 1u)) >> 16);
}
__device__ __forceinline__ float fexp2(float x) {
#if __has_builtin(__builtin_amdgcn_exp2f)
    return __builtin_amdgcn_exp2f(x);
#else
    return exp2f(x);
#endif
}

// ---------------------------------------------------------------------------
// cvt_all: one dispatch for all input conversions (grid 3072).
//   bid [0,2048):    x fp32 -> (xh, xl) bf16 hi/lo split
//   bid [2048,2816): W_attn [C,3C] -> (WaTh, WaTl) bf16 [3C,C] T-split
//   bid [2816,3072): W_proj [C,C]  -> WpT bf16 [C,C] transpose
// ---------------------------------------------------------------------------
__global__ __launch_bounds__(256) void cvt_all(
    const float* __restrict__ x,  short* __restrict__ xh,   short* __restrict__ xl,
    const float* __restrict__ Wa, short* __restrict__ WaTh, short* __restrict__ WaTl,
    const float* __restrict__ Wp, short* __restrict__ WpT)
{
    __shared__ short th[64][80];
    __shared__ short tl[64][80];
    const int tid = threadIdx.x;
    const int bid = blockIdx.x;

    if (bid < 2048) {
        // ---- x hi/lo split (16 MB fp32 -> 2x 8 MB bf16) ----
        int i = (bid * 256 + tid) * 8;
        float4 a = *(const float4*)&x[i];
        float4 b = *(const float4*)&x[i + 4];
        float v[8] = {a.x, a.y, a.z, a.w, b.x, b.y, b.z, b.w};
        s16x8 h, l;
        #pragma unroll
        for (int j = 0; j < 8; j++) {
            unsigned short hb = f2b(v[j]);
            h[j] = (short)hb;
            l[j] = (short)f2b(v[j] - b2f(hb));
        }
        *(s16x8*)&xh[i] = h;
        *(s16x8*)&xl[i] = l;
        return;
    }

    if (bid < 2816) {
        // ---- W_attn transpose + hi/lo split ----
        int r  = bid - 2048;            // 0..767
        int bx = r % 48, by = r / 48;   // (N3_/64, C_/64)
        const int k0 = by * 64, n0 = bx * 64;
        const int R = C_, Cn = N3_;
        {
            int rl = tid >> 4, cl = (tid & 15) * 4;
            #pragma unroll
            for (int i = 0; i < 4; i++) {
                int kr = rl + i * 16;
                float4 v4 = *(const float4*)&Wa[(size_t)(k0 + kr) * Cn + n0 + cl];
                float v[4] = {v4.x, v4.y, v4.z, v4.w};
                #pragma unroll
                for (int j = 0; j < 4; j++) {
                    unsigned short hb = f2b(v[j]);
                    th[cl + j][kr] = (short)hb;
                    tl[cl + j][kr] = (short)f2b(v[j] - b2f(hb));
                }
            }
        }
        __syncthreads();
        {
            int ro = tid >> 2, co = (tid & 3) * 16;
            *(s16x8*)&WaTh[(size_t)(n0 + ro) * R + k0 + co]     = *(s16x8*)&th[ro][co];
            *(s16x8*)&WaTh[(size_t)(n0 + ro) * R + k0 + co + 8] = *(s16x8*)&th[ro][co + 8];
            *(s16x8*)&WaTl[(size_t)(n0 + ro) * R + k0 + co]     = *(s16x8*)&tl[ro][co];
            *(s16x8*)&WaTl[(size_t)(n0 + ro) * R + k0 + co + 8] = *(s16x8*)&tl[ro][co + 8];
        }
        return;
    }

    {
        // ---- W_proj transpose (single bf16) ----
        int r  = bid - 2816;            // 0..255
        int bx = r & 15, by = r >> 4;   // (C_/64, C_/64)
        const int k0 = by * 64, n0 = bx * 64;
        const int R = C_, Cn = C_;
        {
            int rl = tid >> 4, cl = (tid & 15) * 4;
            #pragma unroll
            for (int i = 0; i < 4; i++) {
                int kr = rl + i * 16;
                float4 v = *(const float4*)&Wp[(size_t)(k0 + kr) * Cn + n0 + cl];
                th[cl + 0][kr] = (short)f2b(v.x);
                th[cl + 1][kr] = (short)f2b(v.y);
                th[cl + 2][kr] = (short)f2b(v.z);
                th[cl + 3][kr] = (short)f2b(v.w);
            }
        }
        __syncthreads();
        {
            int ro = tid >> 2, co = (tid & 3) * 16;
            *(s16x8*)&WpT[(size_t)(n0 + ro) * R + k0 + co]     = *(s16x8*)&th[ro][co];
            *(s16x8*)&WpT[(size_t)(n0 + ro) * R + k0 + co + 8] = *(s16x8*)&th[ro][co + 8];
        }
    }
}

// ---------------------------------------------------------------------------
// qkv_qk: Q,K columns (N=2048), bf16x3, hi/lo scatter. Q pre-scaled by
// 8*log2(e). 128x128 tile, grid (16,32), XCD remap. BK=64: two 32-wide
// panels per barrier-pair (16 staging phases instead of 32). LDS 64 KB.
// 0-conflict granule swizzle per panel.
// ---------------------------------------------------------------------------
__global__ __launch_bounds__(256) void qkv_qk(
    const short* __restrict__ Ah, const short* __restrict__ Al,
    const short* __restrict__ BTh, const short* __restrict__ BTl,
    const float* __restrict__ bias,
    short* __restrict__ Qh, short* __restrict__ Ql,
    short* __restrict__ Kh, short* __restrict__ Kl)
{
    __shared__ short Ash[2][128 * 32], Asl[2][128 * 32];
    __shared__ short Bsh[2][128 * 32], Bsl[2][128 * 32];   // 64 KB

    const int tid  = threadIdx.x;
    const int wave = tid >> 6, lane = tid & 63;
    const int wm = wave >> 1, wn = wave & 1;
    const int lm = lane & 15, lq = lane >> 4;
    // XCD-aware bijective remap: 512 blocks, 64 consecutive tiles per XCD
    const int fid = blockIdx.y * 16 + blockIdx.x;
    const int wg  = (fid & 7) * 64 + (fid >> 3);
    const int n0  = (wg & 15) * 128;
    const int m0  = (wg >> 4) * 128;
    const int gr  = (lane >> 2);
    // swizzled SOURCE granule: slot (row,g) holds global granule g^((row>>1)&3)
    const int gc  = (((lane & 3) ^ ((lane >> 3) & 3)) << 3);
    // swizzled READ col: logical granule lq of row-in-seg lm lives at lq^((lm>>1)&3)
    const int sg  = ((lq ^ ((lm >> 1) & 3)) << 3);

    f32x4 acc[4][4] = {};

    for (int k0 = 0; k0 < C_; k0 += 64) {
        __syncthreads();
        #pragma unroll
        for (int p = 0; p < 2; p++) {
            int kp = k0 + p * 32;
            #pragma unroll
            for (int j = 0; j < 2; j++) {
                int s = wave * 2 + j;
                int row = s * 16 + gr;
                size_t ga = (size_t)(m0 + row) * C_ + kp + gc;
                size_t gb = (size_t)(n0 + row) * C_ + kp + gc;
                gload_lds16(&Ah[ga],  &Ash[p][s * 512]);
                gload_lds16(&Al[ga],  &Asl[p][s * 512]);
                gload_lds16(&BTh[gb], &Bsh[p][s * 512]);
                gload_lds16(&BTl[gb], &Bsl[p][s * 512]);
            }
        }
        __syncthreads();

        #pragma unroll
        for (int p = 0; p < 2; p++) {
            s16x8 ah[4], al[4], bh[4], bl[4];
            #pragma unroll
            for (int mi = 0; mi < 4; mi++) {
                int r = wm * 64 + mi * 16 + lm;
                ah[mi] = *(const s16x8*)&Ash[p][r * 32 + sg];
                al[mi] = *(const s16x8*)&Asl[p][r * 32 + sg];
            }
            #pragma unroll
            for (int nj = 0; nj < 4; nj++) {
                int r = wn * 64 + nj * 16 + lm;
                bh[nj] = *(const s16x8*)&Bsh[p][r * 32 + sg];
                bl[nj] = *(const s16x8*)&Bsl[p][r * 32 + sg];
            }
            #pragma unroll
            for (int mi = 0; mi < 4; mi++)
                #pragma unroll
                for (int nj = 0; nj < 4; nj++) {
                    acc[mi][nj] = MFMA16(ah[mi], bh[nj], acc[mi][nj]);
                    acc[mi][nj] = MFMA16(ah[mi], bl[nj], acc[mi][nj]);
                    acc[mi][nj] = MFMA16(al[mi], bh[nj], acc[mi][nj]);
                }
        }
    }

    #pragma unroll
    for (int nj = 0; nj < 4; nj++) {
        int n = n0 + wn * 64 + nj * 16 + lm;
        float bv = bias[n];
        int isK = n >> 10;
        int c = n & (C_ - 1);
        int h = c >> 6, d = c & (D_ - 1);
        short* dh = isK ? Kh : Qh;
        short* dl = isK ? Kl : Ql;
        // Q carries sqrt(D)=8 and log2(e): softmax runs in exp2 domain
        float scale = isK ? 1.0f : 11.541560327111708f;   // 8*log2(e)
        #pragma unroll
        for (int mi = 0; mi < 4; mi++) {
            #pragma unroll
            for (int r = 0; r < 4; r++) {
                int m  = m0 + wm * 64 + mi * 16 + lq * 4 + r;
                int bb = m >> 11, t = m & (T_ - 1);
                float v = (acc[mi][nj][r] + bv) * scale;
                size_t idx = (((size_t)bb * H_ + h) * T_ + t) * D_ + d;
                unsigned short hb = f2b(v);
                dh[idx] = (short)hb;
                dl[idx] = (short)f2b(v - b2f(hb));
            }
        }
    }
}

// ---------------------------------------------------------------------------
// qkv_v: V columns (N=1024), single bf16, scatter TRANSPOSED -> VT [B,H,D,T].
// 64x128 tile, grid (8,64), XCD remap. BK=64 panels, LDS 24 KB.
// ---------------------------------------------------------------------------
__global__ __launch_bounds__(256, 4) void qkv_v(
    const short* __restrict__ Ah, const short* __restrict__ BTh,
    const float* __restrict__ bias, short* __restrict__ VT)
{
    __shared__ short Ash[2][64 * 32];    // 8 KB
    __shared__ short Bsh[2][128 * 32];   // 16 KB

    const int tid  = threadIdx.x;
    const int wave = tid >> 6, lane = tid & 63;
    const int wm = wave >> 1, wn = wave & 1;
    const int lm = lane & 15, lq = lane >> 4;
    // XCD remap: 512 blocks, 64 consecutive tiles per XCD
    const int fid = blockIdx.y * 8 + blockIdx.x;
    const int wg  = (fid & 7) * 64 + (fid >> 3);
    const int n0  = (wg & 7) * 128;
    const int m0  = (wg >> 3) * 64;
    const int gr  = (lane >> 2);
    const int gc  = (((lane & 3) ^ ((lane >> 3) & 3)) << 3);
    const int sg  = ((lq ^ ((lm >> 1) & 3)) << 3);

    f32x4 acc[2][4] = {};

    for (int k0 = 0; k0 < C_; k0 += 64) {
        __syncthreads();
        #pragma unroll
        for (int p = 0; p < 2; p++) {
            int kp = k0 + p * 32;
            int rowA = wave * 16 + gr;
            gload_lds16(&Ah[(size_t)(m0 + rowA) * C_ + kp + gc], &Ash[p][wave * 512]);
            #pragma unroll
            for (int j = 0; j < 2; j++) {
                int s = wave * 2 + j;
                int rowB = s * 16 + gr;
                gload_lds16(&BTh[(size_t)(n0 + rowB) * C_ + kp + gc], &Bsh[p][s * 512]);
            }
        }
        __syncthreads();

        #pragma unroll
        for (int p = 0; p < 2; p++) {
            s16x8 af[2], bfr[4];
            #pragma unroll
            for (int mi = 0; mi < 2; mi++)
                af[mi] = *(const s16x8*)&Ash[p][(wm * 32 + mi * 16 + lm) * 32 + sg];
            #pragma unroll
            for (int nj = 0; nj < 4; nj++)
                bfr[nj] = *(const s16x8*)&Bsh[p][(wn * 64 + nj * 16 + lm) * 32 + sg];
            #pragma unroll
            for (int mi = 0; mi < 2; mi++)
                #pragma unroll
                for (int nj = 0; nj < 4; nj++)
                    acc[mi][nj] = MFMA16(af[mi], bfr[nj], acc[mi][nj]);
        }
    }

    #pragma unroll
    for (int nj = 0; nj < 4; nj++) {
        int n = n0 + wn * 64 + nj * 16 + lm;    // [0, 1024) V channel
        float bv = bias[n];
        int h = n >> 6, d = n & (D_ - 1);
        #pragma unroll
        for (int mi = 0; mi < 2; mi++) {
            #pragma unroll
            for (int r = 0; r < 4; r++) {
                int m  = m0 + wm * 32 + mi * 16 + lq * 4 + r;
                int bb = m >> 11, t = m & (T_ - 1);
                VT[(((size_t)bb * H_ + h) * D_ + d) * T_ + t] =
                    (short)f2b(acc[mi][nj][r] + bv);
            }
        }
    }
}

// ---------------------------------------------------------------------------
// proj: out fp32 [M,C] = Yb(bf16) @ WpT(bf16) + bias. 64x128 tile, grid 512,
// XCD remap. BK=64 panels, LDS 24 KB.
// ---------------------------------------------------------------------------
__global__ __launch_bounds__(256, 4) void proj_mfma(
    const short* __restrict__ Ah, const short* __restrict__ BTh,
    const float* __restrict__ bias, float* __restrict__ out)
{
    __shared__ short Ash[2][64 * 32];
    __shared__ short Bsh[2][128 * 32];

    const int tid  = threadIdx.x;
    const int wave = tid >> 6, lane = tid & 63;
    const int wm = wave >> 1, wn = wave & 1;
    const int lm = lane & 15, lq = lane >> 4;
    const int fid = blockIdx.y * 8 + blockIdx.x;
    const int wg  = (fid & 7) * 64 + (fid >> 3);
    const int n0  = (wg & 7) * 128;
    const int m0  = (wg >> 3) * 64;
    const int gr  = (lane >> 2);
    const int gc  = (((lane & 3) ^ ((lane >> 3) & 3)) << 3);
    const int sg  = ((lq ^ ((lm >> 1) & 3)) << 3);

    f32x4 acc[2][4] = {};

    for (int k0 = 0; k0 < C_; k0 += 64) {
        __syncthreads();
        #pragma unroll
        for (int p = 0; p < 2; p++) {
            int kp = k0 + p * 32;
            int rowA = wave * 16 + gr;
            gload_lds16(&Ah[(size_t)(m0 + rowA) * C_ + kp + gc], &Ash[p][wave * 512]);
            #pragma unroll
            for (int j = 0; j < 2; j++) {
                int s = wave * 2 + j;
                int rowB = s * 16 + gr;
                gload_lds16(&BTh[(size_t)(n0 + rowB) * C_ + kp + gc], &Bsh[p][s * 512]);
            }
        }
        __syncthreads();

        #pragma unroll
        for (int p = 0; p < 2; p++) {
            s16x8 af[2], bfr[4];
            #pragma unroll
            for (int mi = 0; mi < 2; mi++)
                af[mi] = *(const s16x8*)&Ash[p][(wm * 32 + mi * 16 + lm) * 32 + sg];
            #pragma unroll
            for (int nj = 0; nj < 4; nj++)
                bfr[nj] = *(const s16x8*)&Bsh[p][(wn * 64 + nj * 16 + lm) * 32 + sg];
            #pragma unroll
            for (int mi = 0; mi < 2; mi++)
                #pragma unroll
                for (int nj = 0; nj < 4; nj++)
                    acc[mi][nj] = MFMA16(af[mi], bfr[nj], acc[mi][nj]);
        }
    }

    #pragma unroll
    for (int nj = 0; nj < 4; nj++) {
        int n = n0 + wn * 64 + nj * 16 + lm;
        float bv = bias[n];
        #pragma unroll
        for (int mi = 0; mi < 2; mi++) {
            #pragma unroll
            for (int r = 0; r < 4; r++) {
                int m = m0 + wm * 32 + mi * 16 + lq * 4 + r;
                out[(size_t)m * C_ + n] = acc[mi][nj][r] + bv;
            }
        }
    }
}

// ---------------------------------------------------------------------------
// online softmax (exp2 domain) with defer-max (THR=8). S in/out: S^T frag,
// per-thread 16 values for q-row lm. On exit S holds P = exp2(S - m).
// ---------------------------------------------------------------------------
__device__ __forceinline__ void online_sm(
    f32x4 S[4], float& mrow, float& lrow, f32x4 O[4], int quad)
{
    float v[16];
    #pragma unroll
    for (int t = 0; t < 4; t++)
        #pragma unroll
        for (int r = 0; r < 4; r++) v[t * 4 + r] = S[t][r];
    #pragma unroll
    for (int s = 8; s; s >>= 1)
        #pragma unroll
        for (int i = 0; i < s; i++) v[i] = fmaxf(v[i], v[i + s]);
    float rm = v[0];
    rm = fmaxf(rm, __shfl_xor(rm, 16, 64));
    rm = fmaxf(rm, __shfl_xor(rm, 32, 64));
    // defer-max: only rescale when some row grew by > 8 (=2^8 headroom)
    if (!__all(rm - mrow <= 8.f)) {
        float mnew  = fmaxf(mrow, rm);
        float alpha = fexp2(mrow - mnew);
        mrow = mnew;
        lrow *= alpha;
        float al[4];
        #pragma unroll
        for (int r = 0; r < 4; r++) al[r] = __shfl(alpha, quad * 4 + r, 64);
        #pragma unroll
        for (int t = 0; t < 4; t++)
            #pragma unroll
            for (int r = 0; r < 4; r++) O[t][r] *= al[r];
    }
    float sv[16];
    #pragma unroll
    for (int t = 0; t < 4; t++)
        #pragma unroll
        for (int r = 0; r < 4; r++) {
            float p = fexp2(S[t][r] - mrow);
            S[t][r] = p;
            sv[t * 4 + r] = p;
        }
    #pragma unroll
    for (int s = 8; s; s >>= 1)
        #pragma unroll
        for (int i = 0; i < s; i++) sv[i] += sv[i + s];
    float rs = sv[0];
    rs += __shfl_xor(rs, 16, 64);
    rs += __shfl_xor(rs, 32, 64);
    lrow += rs;
}

// ---------------------------------------------------------------------------
// MFMA flash attention, S^T layout, PAIRED q-tiles per block. Grid 512.
// Block handles qtA=j (j in 0..15) and qtB=31-j of one (b,h): exactly 33
// compute-units each. K/V staged once per kt, shared by both tiles; for
// kt<=j one LDS k-frag read feeds 6 MFMAs (dual chains = intra-wave ILP).
// Slot map pairs j with 15-j -> per-CU iteration count 49 (constant).
// LDS 40KB, XOR-swizzled [64][64] (conflict-free), 2 blocks/CU.
// Q pre-scaled by 8*log2e; softmax exp2-domain with defer-max. (R17-exact)
// ---------------------------------------------------------------------------
__global__ __launch_bounds__(256, 2) void attn_mfma(
    const short* __restrict__ Qh, const short* __restrict__ Ql,
    const short* __restrict__ Kh, const short* __restrict__ Kl,
    const short* __restrict__ VT, short* __restrict__ Yb)
{
    __shared__ short Ksh[64][64], Ksl[64][64];   // [key][d], XOR-swizzled
    __shared__ short Vt [64][64];                // [d][key], XOR-swizzled
    __shared__ short Ps [4][2][16][64];          // per-wave P slabs (B=0,A=1)

    const int tid  = threadIdx.x;
    const int wave = tid >> 6, lane = tid & 63;
    const int lm   = lane & 15, quad = lane >> 4;
    const int swz  = (lm & 7) << 3;              // read-side XOR (shorts)

    const int bid = blockIdx.x;                  // 512 blocks
    const int xcd = bid & 7;
    const int r_  = bid >> 3;                    // 0..63 per XCD
    const int bhl = r_ & 3;
    const int u   = r_ >> 2;                     // 0..15
    const int g_  = u >> 3, j_ = u & 7;
    const int j   = g_ ? (15 - j_) : j_;         // CU slot pairs j with 15-j
    const int bh  = xcd * 4 + bhl;
    const int b   = bh >> 4, h = bh & (H_ - 1);
    const int qtA = j, qtB = 31 - j;
    const int q0A = qtA * 64, q0B = qtB * 64;
    const size_t base  = (size_t)bh * T_ * D_;   // Q,K: [b,h,t,d]
    const size_t vbase = (size_t)bh * D_ * T_;   // VT:  [b,h,d,t]

    const int src = tid >> 3;                    // staging row 0..31 (+32)
    const int sch = (tid & 7) * 8;               // linear global col (shorts)
    const int wsw = sch ^ ((src & 7) << 3);      // swizzled LDS write col

    // ---- Q frags direct from global (L2-hit, once per block) ----
    s16x8 bqhA[2], bqlA[2], bqhB[2], bqlB[2];
    #pragma unroll
    for (int kc = 0; kc < 2; kc++) {
        size_t ga = base + (size_t)(q0A + wave * 16 + lm) * D_ + kc * 32 + quad * 8;
        size_t gb = base + (size_t)(q0B + wave * 16 + lm) * D_ + kc * 32 + quad * 8;
        bqhA[kc] = *(const s16x8*)&Qh[ga];
        bqlA[kc] = *(const s16x8*)&Ql[ga];
        bqhB[kc] = *(const s16x8*)&Qh[gb];
        bqlB[kc] = *(const s16x8*)&Ql[gb];
    }

    // ---- prefetch k-tile 0 into registers ----
    s16x8 pkh[2], pkl[2], pvt[2];
    #pragma unroll
    for (int i = 0; i < 2; i++) {
        int row = i * 32 + src;
        size_t gk = base + (size_t)row * D_ + sch;
        pkh[i] = *(const s16x8*)&Kh[gk];
        pkl[i] = *(const s16x8*)&Kl[gk];
        pvt[i] = *(const s16x8*)&VT[vbase + (size_t)row * T_ + sch];
    }

    float mA = -INFINITY, lA = 0.f;
    float mB = -INFINITY, lB = 0.f;
    f32x4 OA[4] = {}, OB[4] = {};

    for (int kt = 0; kt <= qtB; kt++) {
        __syncthreads();                          // prev tile's readers done
        #pragma unroll
        for (int i = 0; i < 2; i++) {             // VGPR -> LDS (swizzled)
            int row = i * 32 + src;
            *(s16x8*)&Ksh[row][wsw] = pkh[i];
            *(s16x8*)&Ksl[row][wsw] = pkl[i];
            *(s16x8*)&Vt [row][wsw] = pvt[i];
        }
        if (kt < qtB) {                           // issue next tile's loads
            #pragma unroll
            for (int i = 0; i < 2; i++) {
                int row = i * 32 + src;
                size_t gk = base + (size_t)((kt + 1) * 64 + row) * D_ + sch;
                pkh[i] = *(const s16x8*)&Kh[gk];
                pkl[i] = *(const s16x8*)&Kl[gk];
                pvt[i] = *(const s16x8*)&VT[vbase + (size_t)row * T_ + (kt + 1) * 64 + sch];
            }
        }
        __syncthreads();

        const bool doA = (kt <= qtA);
        const int  qg  = wave * 16 + lm;

        f32x4 SB[4] = {}, SA[4] = {};
        if (doA) {
            // dual: one k-frag read feeds 6 MFMAs (two independent chains)
            #pragma unroll
            for (int t = 0; t < 4; t++)
                #pragma unroll
                for (int kc = 0; kc < 2; kc++) {
                    s16x8 kh8 = *(const s16x8*)&Ksh[t * 16 + lm][(kc * 32 + quad * 8) ^ swz];
                    s16x8 kl8 = *(const s16x8*)&Ksl[t * 16 + lm][(kc * 32 + quad * 8) ^ swz];
                    SB[t] = MFMA16(kh8, bqhB[kc], SB[t]);
                    SB[t] = MFMA16(kl8, bqhB[kc], SB[t]);
                    SB[t] = MFMA16(kh8, bqlB[kc], SB[t]);
                    SA[t] = MFMA16(kh8, bqhA[kc], SA[t]);
                    SA[t] = MFMA16(kl8, bqhA[kc], SA[t]);
                    SA[t] = MFMA16(kh8, bqlA[kc], SA[t]);
                }
        } else {
            #pragma unroll
            for (int t = 0; t < 4; t++)
                #pragma unroll
                for (int kc = 0; kc < 2; kc++) {
                    s16x8 kh8 = *(const s16x8*)&Ksh[t * 16 + lm][(kc * 32 + quad * 8) ^ swz];
                    s16x8 kl8 = *(const s16x8*)&Ksl[t * 16 + lm][(kc * 32 + quad * 8) ^ swz];
                    SB[t] = MFMA16(kh8, bqhB[kc], SB[t]);
                    SB[t] = MFMA16(kl8, bqhB[kc], SB[t]);
                    SB[t] = MFMA16(kh8, bqlB[kc], SB[t]);
                }
        }

        // causal masks (scale pre-folded into Q)
        if (kt == qtB) {
            #pragma unroll
            for (int t = 0; t < 4; t++)
                #pragma unroll
                for (int r = 0; r < 4; r++)
                    if ((t * 16 + quad * 4 + r) > qg) SB[t][r] = -INFINITY;
        }
        if (kt == qtA) {
            #pragma unroll
            for (int t = 0; t < 4; t++)
                #pragma unroll
                for (int r = 0; r < 4; r++)
                    if ((t * 16 + quad * 4 + r) > qg) SA[t][r] = -INFINITY;
        }

        // ---- softmax (dual chains are independent) ----
        online_sm(SB, mB, lB, OB, quad);
        if (doA) online_sm(SA, mA, lA, OA, quad);

        // ---- P^T -> Ps (truncating bf16; P in [0, 256]) ----
        #pragma unroll
        for (int t = 0; t < 4; t++) {
            s16x4 p;
            #pragma unroll
            for (int r = 0; r < 4; r++)
                p[r] = (short)(__float_as_uint(SB[t][r]) >> 16);
            *(s16x4*)&Ps[wave][0][lm][(t * 16 + quad * 4) ^ swz] = p;
        }
        if (doA) {
            #pragma unroll
            for (int t = 0; t < 4; t++) {
                s16x4 p;
                #pragma unroll
                for (int r = 0; r < 4; r++)
                    p[r] = (short)(__float_as_uint(SA[t][r]) >> 16);
                *(s16x4*)&Ps[wave][1][lm][(t * 16 + quad * 4) ^ swz] = p;
            }
        }
        // wave-private slabs: no barrier (lgkmcnt ordering within wave)

        // ---- O += P V: shared Vt frag feeds both tiles ----
        s16x8 apB[2], apA[2];
        #pragma unroll
        for (int kc = 0; kc < 2; kc++)
            apB[kc] = *(const s16x8*)&Ps[wave][0][lm][(kc * 32 + quad * 8) ^ swz];
        if (doA) {
            #pragma unroll
            for (int kc = 0; kc < 2; kc++)
                apA[kc] = *(const s16x8*)&Ps[wave][1][lm][(kc * 32 + quad * 8) ^ swz];
            #pragma unroll
            for (int t = 0; t < 4; t++)
                #pragma unroll
                for (int kc = 0; kc < 2; kc++) {
                    s16x8 bv = *(const s16x8*)&Vt[t * 16 + lm][(kc * 32 + quad * 8) ^ swz];
                    OB[t] = MFMA16(apB[kc], bv, OB[t]);
                    OA[t] = MFMA16(apA[kc], bv, OA[t]);
                }
        } else {
            #pragma unroll
            for (int t = 0; t < 4; t++)
                #pragma unroll
                for (int kc = 0; kc < 2; kc++) {
                    s16x8 bv = *(const s16x8*)&Vt[t * 16 + lm][(kc * 32 + quad * 8) ^ swz];
                    OB[t] = MFMA16(apB[kc], bv, OB[t]);
                }
        }
    }

    // ---- epilogue: O row q = wave*16+quad*4+r, col d = t*16+lm ----
    float liA[4], liB[4];
    #pragma unroll
    for (int r = 0; r < 4; r++) {
        liA[r] = 1.0f / __shfl(lA, quad * 4 + r, 64);
        liB[r] = 1.0f / __shfl(lB, quad * 4 + r, 64);
    }
    #pragma unroll
    for (int t = 0; t < 4; t++)
        #pragma unroll
        for (int r = 0; r < 4; r++) {
            int d  = t * 16 + lm;
            int qa = q0A + wave * 16 + quad * 4 + r;
            int qb = q0B + wave * 16 + quad * 4 + r;
            Yb[((size_t)b * T_ + qa) * C_ + h * D_ + d] =
                (short)f2b(OA[t][r] * liA[r]);
            Yb[((size_t)b * T_ + qb) * C_ + h * D_ + d] =
                (short)f2b(OB[t][r] * liB[r]);
        }
}

// ---------------------------------------------------------------------------
extern "C" void kernel_launch(void* const* d_in, const int* in_sizes, int n_in,
                              void* d_out, int out_size, void* d_ws, size_t ws_size,
                              hipStream_t stream)
{
    const float* x      = (const float*)d_in[0];
    const float* W_attn = (const float*)d_in[1];
    const float* b_attn = (const float*)d_in[2];
    const float* W_proj = (const float*)d_in[3];
    const float* b_proj = (const float*)d_in[4];
    float* out = (float*)d_out;

    char* ws = (char*)d_ws;
    const size_t MB = 1024 * 1024;
    short* Qh   = (short*)(ws);            // 8 MB  [ 0, 8)
    short* Ql   = (short*)(ws +  8 * MB);  // 8 MB  [ 8,16)
    short* Kh   = (short*)(ws + 16 * MB);  // 8 MB  [16,24)
    short* Kl   = (short*)(ws + 24 * MB);  // 8 MB  [24,32)
    short* xh   = (short*)(ws + 32 * MB);  // 8 MB  [32,40)  dead after qkv_v
    short* xl   = (short*)(ws + 40 * MB);  // 8 MB  [40,48)  dead after qkv_qk
    short* WaTh = (short*)(ws + 48 * MB);  // 6 MB  [48,54)
    short* WaTl = (short*)(ws + 54 * MB);  // 6 MB  [54,60)
    short* WpT  = (short*)(ws + 60 * MB);  // 2 MB  [60,62)
    short* VT   = (short*)(ws + 40 * MB);  // 8 MB  aliases xl (born at qkv_v)
    short* Yb   = (short*)(ws + 32 * MB);  // 8 MB  aliases xh (born at attn)

    cvt_all<<<dim3(3072), 256, 0, stream>>>(x, xh, xl, W_attn, WaTh, WaTl,
                                            W_proj, WpT);

    qkv_qk <<<dim3(16, 32), 256, 0, stream>>>(xh, xl, WaTh, WaTl, b_attn,
                                              Qh, Ql, Kh, Kl);
    qkv_v  <<<dim3(8, 64), 256, 0, stream>>>(xh, WaTh + (size_t)2048 * C_,
                                             b_attn + 2048, VT);
    attn_mfma<<<dim3(512), 256, 0, stream>>>(Qh, Ql, Kh, Kl, VT, Yb);
    proj_mfma<<<dim3(8, 64), 256, 0, stream>>>(Yb, WpT, b_proj, out);
}